// Round 1
// baseline (2387.989 us; speedup 1.0000x reference)
//
#include <hip/hip_runtime.h>
#include <math.h>

#define B_ 2
#define C_ 8
#define H_ 512
#define W_ 1024
#define NH_ 8
#define DH_ 64
#define NE_ (B_*C_*H_*W_)          // 8388608
#define NBCN_ (B_*C_*NH_)          // 128
#define SCALE_ 0.044194173824159216f   // 1/sqrt(512)

// ---------------------------------------------------------------------------
// mclin: Y[bc][o][w] = sum_h Wt[c][o][h] * X[bc][h][w]
// grid (W/64, H/64, B*C), block 256.  64x64 tile, K-tiles of 16, 4x4/thread.
// ---------------------------------------------------------------------------
__global__ __launch_bounds__(256) void mclin_kernel(const float* __restrict__ X,
                                                    const float* __restrict__ Wt,
                                                    float* __restrict__ Y) {
    int bc = blockIdx.z;
    int c  = bc % C_;
    int o0 = blockIdx.y * 64;
    int w0 = blockIdx.x * 64;
    const float* Xp = X + (size_t)bc * H_ * W_;
    const float* Wp = Wt + (size_t)c * H_ * H_;
    float* Yp = Y + (size_t)bc * H_ * W_;

    __shared__ float As[16][65];   // As[kk][oo]
    __shared__ float Bs[16][65];   // Bs[kk][ww]
    int t  = threadIdx.x;
    int tx = t % 16, ty = t / 16;
    float acc[4][4] = {};

    for (int k0 = 0; k0 < H_; k0 += 16) {
        #pragma unroll
        for (int rep = 0; rep < 4; rep++) {
            int idx = t + rep * 256;
            int oo = idx / 16, kk = idx % 16;
            As[kk][oo] = Wp[(size_t)(o0 + oo) * H_ + k0 + kk];
        }
        #pragma unroll
        for (int rep = 0; rep < 4; rep++) {
            int idx = t + rep * 256;
            int kk = idx / 64, ww = idx % 64;
            Bs[kk][ww] = Xp[(size_t)(k0 + kk) * W_ + w0 + ww];
        }
        __syncthreads();
        #pragma unroll
        for (int kk = 0; kk < 16; kk++) {
            float a[4], b[4];
            #pragma unroll
            for (int i = 0; i < 4; i++) a[i] = As[kk][ty * 4 + i];
            #pragma unroll
            for (int j = 0; j < 4; j++) b[j] = Bs[kk][tx * 4 + j];
            #pragma unroll
            for (int i = 0; i < 4; i++)
                #pragma unroll
                for (int j = 0; j < 4; j++) acc[i][j] += a[i] * b[j];
        }
        __syncthreads();
    }
    #pragma unroll
    for (int i = 0; i < 4; i++) {
        float4 v = make_float4(acc[i][0], acc[i][1], acc[i][2], acc[i][3]);
        *(float4*)&Yp[(size_t)(o0 + ty * 4 + i) * W_ + w0 + tx * 4] = v;
    }
}

// ---------------------------------------------------------------------------
// conv (1,3), padding (0,1), channel-mixing + bias.  One thread per output.
// ---------------------------------------------------------------------------
__global__ __launch_bounds__(256) void conv_kernel(const float* __restrict__ Yin,
                                                   const float* __restrict__ Kc,
                                                   const float* __restrict__ bias,
                                                   float* __restrict__ Z) {
    size_t idx = (size_t)blockIdx.x * 256 + threadIdx.x;
    int w = idx % W_; size_t r = idx / W_;
    int h = r % H_; r /= H_;
    int co = r % C_; int b = r / C_;
    float acc = bias[co];
    #pragma unroll
    for (int ci = 0; ci < C_; ci++) {
        const float* yrow = Yin + ((size_t)(b * C_ + ci) * H_ + h) * W_;
        const float* kp = Kc + (co * C_ + ci) * 3;
        float k0 = kp[0], k1 = kp[1], k2 = kp[2];
        if (w > 0)      acc += yrow[w - 1] * k0;
        acc += yrow[w] * k1;
        if (w < W_ - 1) acc += yrow[w + 1] * k2;
    }
    Z[idx] = acc;
}

// ---------------------------------------------------------------------------
// RoPE in-place on Zq and Zk.  One thread per (pair, w) position, both arrays.
// h = n*64 + 2i (x1) and +1 (x2); ang = w * 10000^(-2i/64).
// ---------------------------------------------------------------------------
__global__ __launch_bounds__(256) void rope_kernel(float* __restrict__ Zq,
                                                   float* __restrict__ Zk) {
    size_t idx = (size_t)blockIdx.x * 256 + threadIdx.x;  // over NE_/2
    int w = idx % W_; size_t r = idx / W_;
    int i = r % (DH_ / 2); r /= (DH_ / 2);
    int n = r % NH_; int bc = r / NH_;
    double inv = pow(10000.0, -(double)(2 * i) / (double)DH_);
    double ang = (double)w * inv;
    float cv = (float)cos(ang);
    float sv = (float)sin(ang);
    size_t off = ((size_t)bc * H_ + n * DH_ + 2 * i) * W_ + w;
    {
        float x1 = Zq[off], x2 = Zq[off + W_];
        Zq[off]      = x1 * cv - x2 * sv;
        Zq[off + W_] = x2 * cv + x1 * sv;
    }
    {
        float x1 = Zk[off], x2 = Zk[off + W_];
        Zk[off]      = x1 * cv - x2 * sv;
        Zk[off + W_] = x2 * cv + x1 * sv;
    }
}

// ---------------------------------------------------------------------------
// scores: S[q][k] = SCALE * sum_j Zq[h0+j][q] * Zk[h0+j][k]
// grid (W/64 kblocks, W/64 qblocks, 128 bcn), 64x64 tile, K(=dh)=64.
// ---------------------------------------------------------------------------
__global__ __launch_bounds__(256) void scores_kernel(const float* __restrict__ Zq,
                                                     const float* __restrict__ Zk,
                                                     float* __restrict__ qk) {
    int bcn = blockIdx.z;
    int bc = bcn / NH_, n = bcn % NH_;
    int q0 = blockIdx.y * 64;
    int k0 = blockIdx.x * 64;
    const float* Qp = Zq + ((size_t)bc * H_ + n * DH_) * W_;
    const float* Kp = Zk + ((size_t)bc * H_ + n * DH_) * W_;
    float* Sp = qk + (size_t)bcn * W_ * W_;

    __shared__ float Qs[16][65];   // Qs[jj][qq]
    __shared__ float Ks[16][65];   // Ks[jj][kk]
    int t = threadIdx.x;
    int tx = t % 16, ty = t / 16;
    float acc[4][4] = {};

    for (int j0 = 0; j0 < DH_; j0 += 16) {
        #pragma unroll
        for (int rep = 0; rep < 4; rep++) {
            int idx = t + rep * 256;
            int jj = idx / 64, cc = idx % 64;
            Qs[jj][cc] = Qp[(size_t)(j0 + jj) * W_ + q0 + cc];
            Ks[jj][cc] = Kp[(size_t)(j0 + jj) * W_ + k0 + cc];
        }
        __syncthreads();
        #pragma unroll
        for (int jj = 0; jj < 16; jj++) {
            float a[4], b[4];
            #pragma unroll
            for (int i = 0; i < 4; i++) a[i] = Qs[jj][ty * 4 + i];
            #pragma unroll
            for (int j = 0; j < 4; j++) b[j] = Ks[jj][tx * 4 + j];
            #pragma unroll
            for (int i = 0; i < 4; i++)
                #pragma unroll
                for (int j = 0; j < 4; j++) acc[i][j] += a[i] * b[j];
        }
        __syncthreads();
    }
    #pragma unroll
    for (int i = 0; i < 4; i++) {
        float4 v = make_float4(acc[i][0] * SCALE_, acc[i][1] * SCALE_,
                               acc[i][2] * SCALE_, acc[i][3] * SCALE_);
        *(float4*)&Sp[(size_t)(q0 + ty * 4 + i) * W_ + k0 + tx * 4] = v;
    }
}

// ---------------------------------------------------------------------------
// rowstats: per score-row max and sum(exp(s-max)).  One wave per row.
// ---------------------------------------------------------------------------
__global__ __launch_bounds__(256) void rowstats_kernel(const float* __restrict__ S,
                                                       float* __restrict__ rowmax,
                                                       float* __restrict__ rowsum) {
    size_t row = (size_t)blockIdx.x * 4 + (threadIdx.x >> 6);
    int lane = threadIdx.x & 63;
    const float* Sp = S + row * W_;
    float vals[16];
    float m = -1e30f;
    #pragma unroll
    for (int i = 0; i < 16; i++) { vals[i] = Sp[lane + i * 64]; m = fmaxf(m, vals[i]); }
    #pragma unroll
    for (int off = 32; off; off >>= 1) m = fmaxf(m, __shfl_xor(m, off));
    float s = 0.f;
    #pragma unroll
    for (int i = 0; i < 16; i++) s += expf(vals[i] - m);
    #pragma unroll
    for (int off = 32; off; off >>= 1) s += __shfl_xor(s, off);
    if (lane == 0) { rowmax[row] = m; rowsum[row] = s; }
}

// ---------------------------------------------------------------------------
// av: A[h0+j][q] = sum_k softmax(S)[q][k] * Zv[h0+j][k]
// grid (W/64 qblocks, 128 bcn).  64(q) x 64(j) tile, K(=kw)=1024 in chunks of 16.
// exp applied on the fly using precomputed row stats.
// ---------------------------------------------------------------------------
__global__ __launch_bounds__(256) void av_kernel(const float* __restrict__ S,
                                                 const float* __restrict__ Zv,
                                                 const float* __restrict__ rowmax,
                                                 const float* __restrict__ rowsum,
                                                 float* __restrict__ A) {
    int bcn = blockIdx.y;
    int bc = bcn / NH_, n = bcn % NH_;
    int q0 = blockIdx.x * 64;
    const float* Sp = S + (size_t)bcn * W_ * W_;
    const float* Vp = Zv + ((size_t)bc * H_ + n * DH_) * W_;
    float* Ap = A + ((size_t)bc * H_ + n * DH_) * W_;

    __shared__ float Ps[16][65];   // Ps[kk][qq]  (probabilities)
    __shared__ float Vs[16][65];   // Vs[kk][jj]
    __shared__ float rmax[64], rsc[64];
    int t = threadIdx.x;
    if (t < 64) {
        rmax[t] = rowmax[(size_t)bcn * W_ + q0 + t];
        rsc[t]  = 1.0f / rowsum[(size_t)bcn * W_ + q0 + t];
    }
    __syncthreads();
    int tx = t % 16, ty = t / 16;     // tx -> q groups, ty -> j groups
    float acc[4][4] = {};             // acc[j-sub][q-sub]

    for (int k0 = 0; k0 < W_; k0 += 16) {
        #pragma unroll
        for (int rep = 0; rep < 4; rep++) {
            int idx = t + rep * 256;
            int a = idx / 16, kk = idx % 16;
            float s = Sp[(size_t)(q0 + a) * W_ + k0 + kk];
            Ps[kk][a] = expf(s - rmax[a]) * rsc[a];
            Vs[kk][a] = Vp[(size_t)a * W_ + k0 + kk];
        }
        __syncthreads();
        #pragma unroll
        for (int kk = 0; kk < 16; kk++) {
            float a[4], b[4];
            #pragma unroll
            for (int i = 0; i < 4; i++) a[i] = Vs[kk][ty * 4 + i];   // j
            #pragma unroll
            for (int j = 0; j < 4; j++) b[j] = Ps[kk][tx * 4 + j];   // q
            #pragma unroll
            for (int i = 0; i < 4; i++)
                #pragma unroll
                for (int j = 0; j < 4; j++) acc[i][j] += a[i] * b[j];
        }
        __syncthreads();
    }
    #pragma unroll
    for (int i = 0; i < 4; i++) {
        float4 v = make_float4(acc[i][0], acc[i][1], acc[i][2], acc[i][3]);
        *(float4*)&Ap[(size_t)(ty * 4 + i) * W_ + q0 + tx * 4] = v;
    }
}

// ---------------------------------------------------------------------------
extern "C" void kernel_launch(void* const* d_in, const int* in_sizes, int n_in,
                              void* d_out, int out_size, void* d_ws, size_t ws_size,
                              hipStream_t stream) {
    const float* x  = (const float*)d_in[0];
    const float* wq = (const float*)d_in[1];
    const float* kq = (const float*)d_in[2];
    const float* bq = (const float*)d_in[3];
    const float* wk = (const float*)d_in[4];
    const float* kk = (const float*)d_in[5];
    const float* bk = (const float*)d_in[6];
    const float* wv = (const float*)d_in[7];
    const float* kv = (const float*)d_in[8];
    const float* bv = (const float*)d_in[9];
    const float* wo = (const float*)d_in[10];

    float* out = (float*)d_out;                    // (B,C,H,W)
    float* qk  = out + (size_t)NE_;                // (B,C,NH,W,W)

    float* ws   = (float*)d_ws;
    float* temp = ws;                              // NE_ (mclin out / attn out)
    float* zq   = ws + (size_t)NE_;                // NE_
    float* zk   = ws + (size_t)2 * NE_;            // NE_
    float* zv   = ws + (size_t)3 * NE_;            // NE_
    float* rmax = ws + (size_t)4 * NE_;            // 128*1024
    float* rsum = rmax + (size_t)NBCN_ * W_;       // 128*1024

    dim3 gemmGrid(W_ / 64, H_ / 64, B_ * C_);
    int convBlocks = NE_ / 256;

    // Q path
    mclin_kernel<<<gemmGrid, 256, 0, stream>>>(x, wq, temp);
    conv_kernel<<<convBlocks, 256, 0, stream>>>(temp, kq, bq, zq);
    // K path
    mclin_kernel<<<gemmGrid, 256, 0, stream>>>(x, wk, temp);
    conv_kernel<<<convBlocks, 256, 0, stream>>>(temp, kk, bk, zk);
    // V path
    mclin_kernel<<<gemmGrid, 256, 0, stream>>>(x, wv, temp);
    conv_kernel<<<convBlocks, 256, 0, stream>>>(temp, kv, bv, zv);
    // RoPE on q,k (in place)
    rope_kernel<<<NE_ / 2 / 256, 256, 0, stream>>>(zq, zk);
    // scores -> qk output region
    dim3 scGrid(W_ / 64, W_ / 64, NBCN_);
    scores_kernel<<<scGrid, 256, 0, stream>>>(zq, zk, qk);
    // softmax row stats
    rowstats_kernel<<<NBCN_ * W_ / 4, 256, 0, stream>>>(qk, rmax, rsum);
    // softmax * V  -> temp (in (b,c,h,w) layout)
    dim3 avGrid(W_ / 64, NBCN_);
    av_kernel<<<avGrid, 256, 0, stream>>>(qk, zv, rmax, rsum, temp);
    // output projection
    mclin_kernel<<<gemmGrid, 256, 0, stream>>>(temp, wo, out);
}